// Round 11
// baseline (561.218 us; speedup 1.0000x reference)
//
#include <hip/hip_runtime.h>
#include <hip/hip_cooperative_groups.h>

namespace cg = cooperative_groups;

#define HW 16384   // 128*128
#define RSB 130    // padded row stride (pixels)

typedef short short8 __attribute__((ext_vector_type(8)));
typedef float f32x4 __attribute__((ext_vector_type(4)));
typedef unsigned short ushort8v __attribute__((ext_vector_type(8)));

__device__ __forceinline__ float b2f(unsigned short u) {
    return __uint_as_float(((unsigned)u) << 16);
}
__device__ __forceinline__ unsigned short f2b(float f) {
    unsigned u = __float_as_uint(f);
    return (unsigned short)((u + 0x7fffu + ((u >> 16) & 1u)) >> 16);
}

// workspace offsets (ushort units)
#define O_IN    0                       // in_nhwc 130*130*192 = 3,244,800
#define O_FA    3244800                 // featA   130*130*96  = 1,622,400
#define O_FB    4867200                 // featB
#define O_WBB   6489600                 // wBbot 165,888
#define O_WBO   6655488                 // wBoff 4 x 82,944
#define O_WDB   6987264                 // wdB   4 x 27,648   (end 7,097,856 = 14.2 MB)

// ---------------------------------------------------------------------------
// Stage P: all weight B-fragments (bf16) + NHWC pack + border zeroing.
// Flat-index loop over 1,026,240 items across 131,072 threads.
// Fragment orders verified by r8/r9/r10 passing runs.
// ---------------------------------------------------------------------------
__device__ void prep_work(int gtid,
    const float* __restrict__ X1, const float* __restrict__ X2,
    const float* __restrict__ w_bot,
    const float* __restrict__ wo0, const float* __restrict__ wo1,
    const float* __restrict__ wo2, const float* __restrict__ wo3,
    const float* __restrict__ wd0, const float* __restrict__ wd1,
    const float* __restrict__ wd2, const float* __restrict__ wd3,
    unsigned short* __restrict__ ws) {
    unsigned short* in_nhwc = ws + O_IN;
    unsigned short* featA   = ws + O_FA;
    unsigned short* featB   = ws + O_FB;
    unsigned short* wBbot   = ws + O_WBB;
    unsigned short* wBoff   = ws + O_WBO;
    unsigned short* wdB     = ws + O_WDB;
    const int N0 = 165888, N1 = N0 + 331776, N2 = N1 + 110592,
              N3 = N2 + 393216, N4 = N3 + 24768;
    for (int idx = gtid; idx < N4; idx += 131072) {
        if (idx < N0) {                           // bot conv B-frags (KC=6)
            int i = idx;
            int v = i & 7, lane = (i >> 3) & 63, t = i >> 9;
            int kc = t % 6; t /= 6;
            int tap = t % 9, nt = t / 9;
            int oc = nt * 16 + (lane & 15), cin = kc * 32 + (lane >> 4) * 8 + v;
            wBbot[i] = f2b(oc < 96 ? w_bot[(oc * 192 + cin) * 9 + tap] : 0.f);
        } else if (idx < N1) {                    // offset conv B-frags (KC=3)
            int j = idx - N0;
            int l = j / 82944, i = j - l * 82944;
            const float* w = l == 0 ? wo0 : l == 1 ? wo1 : l == 2 ? wo2 : wo3;
            int v = i & 7, lane = (i >> 3) & 63, t = i >> 9;
            int kc = t % 3; t /= 3;
            int tap = t % 9, nt = t / 9;
            int oc = nt * 16 + (lane & 15), cin = kc * 32 + (lane >> 4) * 8 + v;
            wBoff[j] = f2b(oc < 81 ? w[(oc * 96 + cin) * 9 + tap] : 0.f);
        } else if (idx < N2) {                    // dcn grouped B-frags
            int j = idx - N1;
            int l = j / 27648, i = j - l * 27648;
            const float* w = l == 0 ? wd0 : l == 1 ? wd1 : l == 2 ? wd2 : wd3;
            int v = i & 7, lane = (i >> 3) & 63, t = i >> 9;
            int nt = t & 1; t >>= 1;
            int tap = t % 9, g = t / 9;
            int oc = nt * 16 + (lane & 15), c = (lane >> 4) * 8 + v;
            wdB[j] = f2b(w[((g * 32 + oc) * 32 + c) * 9 + tap]);
        } else if (idx < N3) {                    // pack cat(X1,X2) -> NHWC bf16
            int j = idx - N2;
            int cb = j >> 14, p = j & (HW - 1);
            int ch = cb * 8;
            int y = p >> 7, x = p & 127;
            ushort8v o;
#pragma unroll
            for (int q = 0; q < 8; ++q) {
                int c = ch + q;
                float v = (c < 96) ? X1[c * HW + p] : X2[(c - 96) * HW + p];
                o[q] = f2b(v);
            }
            *(ushort8v*)(in_nhwc + (size_t)((y + 1) * RSB + (x + 1)) * 192 + ch) = o;
        } else {                                  // border zeroing
            int j = idx - N3;
            int bp = j / 48, c8 = j - bp * 48;
            int y, x;
            if (bp < 130)      { y = 0;   x = bp; }
            else if (bp < 260) { y = 129; x = bp - 130; }
            else { int t2 = bp - 260; y = 1 + (t2 >> 1); x = (t2 & 1) ? 129 : 0; }
            size_t pix = (size_t)y * RSB + x;
            ushort8v z = {0, 0, 0, 0, 0, 0, 0, 0};
            if (c8 < 24)      *(ushort8v*)(in_nhwc + pix * 192 + c8 * 8) = z;
            else if (c8 < 36) *(ushort8v*)(featA + pix * 96 + (c8 - 24) * 8) = z;
            else              *(ushort8v*)(featB + pix * 96 + (c8 - 36) * 8) = z;
        }
    }
}

// ---------------------------------------------------------------------------
// Stage B: bottom conv (192 -> 96) as 9-tap implicit MFMA GEMM.
// Block = 64 px, 8 waves = 4 pf x 2 nh subtasks (perfectly balanced).
// ---------------------------------------------------------------------------
__device__ void bot_work(int bid, int tid, const unsigned short* __restrict__ in_nhwc,
                         const unsigned short* __restrict__ wBbot,
                         unsigned short* __restrict__ featA) {
    const int lane = tid & 63;
    const int w = tid >> 6;
    const int pf = w >> 1, nh = w & 1;
    const int col = lane & 15, klane = lane >> 4;
    const int pbase = bid * 64 + pf * 16;
    const int p = pbase + col;
    const int y = p >> 7, x = p & 127;
    const unsigned short* arow = in_nhwc + (size_t)((y + 1) * RSB + (x + 1)) * 192 + klane * 8;
    const unsigned short* wb = wBbot + (size_t)(nh * 3) * 9 * 6 * 512 + lane * 8;

    f32x4 a0 = {0.f, 0.f, 0.f, 0.f};
    f32x4 a1 = {0.f, 0.f, 0.f, 0.f};
    f32x4 a2 = {0.f, 0.f, 0.f, 0.f};
#pragma unroll
    for (int tap = 0; tap < 9; ++tap) {
        const unsigned short* at = arow + ((tap / 3 - 1) * RSB + (tap % 3 - 1)) * 192;
#pragma unroll
        for (int kc = 0; kc < 6; ++kc) {
            short8 a  = *(const short8*)(at + kc * 32);
            short8 b0 = *(const short8*)(wb + ((0 * 9 + tap) * 6 + kc) * 512);
            short8 b1 = *(const short8*)(wb + ((1 * 9 + tap) * 6 + kc) * 512);
            short8 b2 = *(const short8*)(wb + ((2 * 9 + tap) * 6 + kc) * 512);
            a0 = __builtin_amdgcn_mfma_f32_16x16x32_bf16(a, b0, a0, 0, 0, 0);
            a1 = __builtin_amdgcn_mfma_f32_16x16x32_bf16(a, b1, a1, 0, 0, 0);
            a2 = __builtin_amdgcn_mfma_f32_16x16x32_bf16(a, b2, a2, 0, 0, 0);
        }
    }
#pragma unroll
    for (int r = 0; r < 4; ++r) {
        int pr = pbase + klane * 4 + r;
        int yy = pr >> 7, xx = pr & 127;
        size_t base = (size_t)((yy + 1) * RSB + (xx + 1)) * 96;
        featA[base + (nh * 3 + 0) * 16 + col] = f2b(a0[r]);
        featA[base + (nh * 3 + 1) * 16 + col] = f2b(a1[r]);
        featA[base + (nh * 3 + 2) * 16 + col] = f2b(a2[r]);
    }
}

// ---------------------------------------------------------------------------
// Stage L: fused offset-conv + DCN layer (r10-proven).  Block = 64 px, 8 waves.
// Phase A -> raw f32 offsets in LDS; phase B = MFMA DCN with NHWC gathers.
// ---------------------------------------------------------------------------
__device__ void layer_work(int bid, int tid, float (*s_off)[97],
                           const unsigned short* __restrict__ feat,
                           const unsigned short* __restrict__ wBoffL,
                           const unsigned short* __restrict__ wdBL,
                           const float* __restrict__ b_dL,
                           void* __restrict__ outp, int last) {
    const int lane = tid & 63;
    const int w = tid >> 6;
    const int col = lane & 15, klane = lane >> 4;
    const int pb = ((bid & 7) << 5) + (bid >> 3);   // XCD swizzle: 16-row bands
    const int P0 = pb * 64;

    // phase A: offset conv
    {
        const int pf = w >> 1, nh = w & 1;
        const int p = P0 + pf * 16 + col;
        const int y = p >> 7, x = p & 127;
        const unsigned short* arow = feat + (size_t)((y + 1) * RSB + (x + 1)) * 96 + klane * 8;
        const unsigned short* wb = wBoffL + (size_t)(nh * 3) * 9 * 3 * 512 + lane * 8;

        f32x4 a0 = {0.f, 0.f, 0.f, 0.f};
        f32x4 a1 = {0.f, 0.f, 0.f, 0.f};
        f32x4 a2 = {0.f, 0.f, 0.f, 0.f};
#pragma unroll
        for (int tap = 0; tap < 9; ++tap) {
            const unsigned short* at = arow + ((tap / 3 - 1) * RSB + (tap % 3 - 1)) * 96;
#pragma unroll
            for (int kc = 0; kc < 3; ++kc) {
                short8 a  = *(const short8*)(at + kc * 32);
                short8 b0 = *(const short8*)(wb + ((0 * 9 + tap) * 3 + kc) * 512);
                short8 b1 = *(const short8*)(wb + ((1 * 9 + tap) * 3 + kc) * 512);
                short8 b2 = *(const short8*)(wb + ((2 * 9 + tap) * 3 + kc) * 512);
                a0 = __builtin_amdgcn_mfma_f32_16x16x32_bf16(a, b0, a0, 0, 0, 0);
                a1 = __builtin_amdgcn_mfma_f32_16x16x32_bf16(a, b1, a1, 0, 0, 0);
                a2 = __builtin_amdgcn_mfma_f32_16x16x32_bf16(a, b2, a2, 0, 0, 0);
            }
        }
#pragma unroll
        for (int r = 0; r < 4; ++r) {
            int pl = pf * 16 + klane * 4 + r;
            s_off[pl][nh * 48 + 0 * 16 + col] = a0[r];
            s_off[pl][nh * 48 + 1 * 16 + col] = a1[r];
            s_off[pl][nh * 48 + 2 * 16 + col] = a2[r];
        }
    }
    __syncthreads();

    // phase B: DCN
    for (int sidx = w; sidx < 12; sidx += 8) {
        const int pf = sidx & 3, g = sidx >> 2;
        const int p = P0 + pf * 16 + col;
        const int y = p >> 7, x = p & 127;
        const int pl = pf * 16 + col;
        const int coct = klane * 8;

        float dyv[9], dxv[9], mrv[9];
#pragma unroll
        for (int k = 0; k < 9; ++k) {
            dyv[k] = s_off[pl][g * 9 + k];
            dxv[k] = s_off[pl][27 + g * 9 + k];
            mrv[k] = s_off[pl][54 + g * 9 + k];
        }

        const unsigned short* fgc = feat + g * 32 + coct;
        const unsigned short* wb = wdBL + (size_t)g * 9 * 2 * 512 + lane * 8;

        f32x4 acc0 = {0.f, 0.f, 0.f, 0.f};
        f32x4 acc1 = {0.f, 0.f, 0.f, 0.f};

#pragma unroll
        for (int k = 0; k < 9; ++k) {
            float m = 1.f / (1.f + __expf(-mrv[k]));

            float py = dyv[k] + (float)y + (float)(k / 3 - 1);
            float px = dxv[k] + (float)x + (float)(k % 3 - 1);
            float y0f = floorf(py), x0f = floorf(px);
            float fy = py - y0f, fx = px - x0f;

            float vy0 = (y0f >= 0.f   && y0f <= 127.f) ? 1.f : 0.f;
            float vy1 = (y0f >= -1.f  && y0f <= 126.f) ? 1.f : 0.f;
            float vx0 = (x0f >= 0.f   && x0f <= 127.f) ? 1.f : 0.f;
            float vx1 = (x0f >= -1.f  && x0f <= 126.f) ? 1.f : 0.f;

            int iy0r = (int)y0f, ix0r = (int)x0f;
            int iy0 = min(max(iy0r, 0), 127);
            int iy1 = min(max(iy0r + 1, 0), 127);
            int ix0 = min(max(ix0r, 0), 127);
            int ix1 = min(max(ix0r + 1, 0), 127);

            float w00 = (1.f - fy) * (1.f - fx) * vy0 * vx0 * m;
            float w01 = (1.f - fy) * fx        * vy0 * vx1 * m;
            float w10 = fy        * (1.f - fx) * vy1 * vx0 * m;
            float w11 = fy        * fx         * vy1 * vx1 * m;

            int r00 = (iy0 + 1) * RSB + ix0 + 1, r01 = (iy0 + 1) * RSB + ix1 + 1;
            int r10 = (iy1 + 1) * RSB + ix0 + 1, r11 = (iy1 + 1) * RSB + ix1 + 1;
            ushort8v v00 = *(const ushort8v*)(fgc + (size_t)r00 * 96);
            ushort8v v01 = *(const ushort8v*)(fgc + (size_t)r01 * 96);
            ushort8v v10 = *(const ushort8v*)(fgc + (size_t)r10 * 96);
            ushort8v v11 = *(const ushort8v*)(fgc + (size_t)r11 * 96);

            short8 a;
#pragma unroll
            for (int j = 0; j < 8; ++j) {
                float val = w00 * b2f(v00[j]) + w01 * b2f(v01[j])
                          + w10 * b2f(v10[j]) + w11 * b2f(v11[j]);
                a[j] = (short)f2b(val);
            }
            short8 b0 = *(const short8*)(wb + (k * 2 + 0) * 512);
            short8 b1 = *(const short8*)(wb + (k * 2 + 1) * 512);
            acc0 = __builtin_amdgcn_mfma_f32_16x16x32_bf16(a, b0, acc0, 0, 0, 0);
            acc1 = __builtin_amdgcn_mfma_f32_16x16x32_bf16(a, b1, acc1, 0, 0, 0);
        }

#pragma unroll
        for (int r = 0; r < 4; ++r) {
            int pr = P0 + pf * 16 + klane * 4 + r;
            int ch0 = g * 32 + col, ch1 = g * 32 + 16 + col;
            float o0 = acc0[r] + b_dL[ch0];
            float o1 = acc1[r] + b_dL[ch1];
            if (!last) {
                int yy = pr >> 7, xx = pr & 127;
                unsigned short* fo = (unsigned short*)outp;
                size_t base = (size_t)((yy + 1) * RSB + (xx + 1)) * 96;
                fo[base + ch0] = f2b(o0);
                fo[base + ch1] = f2b(o1);
            } else {
                float* fo = (float*)outp;
                fo[(size_t)ch0 * HW + pr] = o0;
                fo[(size_t)ch1 * HW + pr] = o1;
            }
        }
    }
}

// ---------------------------------------------------------------------------
// Cooperative mega-kernel: all stages, grid.sync between them.
// 256 blocks x 512 thr = 1 block/CU (co-residency guaranteed).
// ---------------------------------------------------------------------------
__global__ __launch_bounds__(512, 1) void mega(
    const float* __restrict__ X1, const float* __restrict__ X2,
    const float* __restrict__ w_bot,
    const float* __restrict__ wo0, const float* __restrict__ wo1,
    const float* __restrict__ wo2, const float* __restrict__ wo3,
    const float* __restrict__ wd0, const float* __restrict__ wd1,
    const float* __restrict__ wd2, const float* __restrict__ wd3,
    const float* __restrict__ bd0, const float* __restrict__ bd1,
    const float* __restrict__ bd2, const float* __restrict__ bd3,
    float* __restrict__ dout, unsigned short* __restrict__ ws) {
    __shared__ float s_off[64][97];
    cg::grid_group grid = cg::this_grid();
    const int gtid = blockIdx.x * 512 + threadIdx.x;

    prep_work(gtid, X1, X2, w_bot, wo0, wo1, wo2, wo3, wd0, wd1, wd2, wd3, ws);
    __threadfence(); grid.sync();

    bot_work(blockIdx.x, threadIdx.x, ws + O_IN, ws + O_WBB, ws + O_FA);
    __threadfence(); grid.sync();

#pragma unroll 1
    for (int it = 0; it < 4; ++it) {
        const unsigned short* cur = ((it & 1) == 0) ? ws + O_FA : ws + O_FB;
        unsigned short* nxt       = ((it & 1) == 0) ? ws + O_FB : ws + O_FA;
        const float* bdL = it == 0 ? bd0 : it == 1 ? bd1 : it == 2 ? bd2 : bd3;
        void* outp = (it == 3) ? (void*)dout : (void*)nxt;
        layer_work(blockIdx.x, threadIdx.x, s_off, cur,
                   ws + O_WBO + it * 82944, ws + O_WDB + it * 27648,
                   bdL, outp, it == 3 ? 1 : 0);
        if (it < 3) { __threadfence(); grid.sync(); }
    }
}

// ---------------------------------------------------------------------------
// Fallback wrappers (plain launches) in case cooperative launch is rejected.
// ---------------------------------------------------------------------------
__global__ __launch_bounds__(512) void k_prep(
    const float* X1, const float* X2, const float* w_bot,
    const float* wo0, const float* wo1, const float* wo2, const float* wo3,
    const float* wd0, const float* wd1, const float* wd2, const float* wd3,
    unsigned short* ws) {
    prep_work(blockIdx.x * 512 + threadIdx.x, X1, X2, w_bot,
              wo0, wo1, wo2, wo3, wd0, wd1, wd2, wd3, ws);
}
__global__ __launch_bounds__(512) void k_bot(const unsigned short* in_nhwc,
                                             const unsigned short* wBbot,
                                             unsigned short* featA) {
    bot_work(blockIdx.x, threadIdx.x, in_nhwc, wBbot, featA);
}
__global__ __launch_bounds__(512) void k_layer(const unsigned short* feat,
                                               const unsigned short* wBoffL,
                                               const unsigned short* wdBL,
                                               const float* b_dL,
                                               void* outp, int last) {
    __shared__ float s_off[64][97];
    layer_work(blockIdx.x, threadIdx.x, s_off, feat, wBoffL, wdBL, b_dL, outp, last);
}

// ---------------------------------------------------------------------------
extern "C" void kernel_launch(void* const* d_in, const int* in_sizes, int n_in,
                              void* d_out, int out_size, void* d_ws, size_t ws_size,
                              hipStream_t stream) {
    const float* X1    = (const float*)d_in[0];
    const float* X2    = (const float*)d_in[1];
    const float* w_bot = (const float*)d_in[2];
    const float* wo0 = (const float*)d_in[3],  *wo1 = (const float*)d_in[6],
               *wo2 = (const float*)d_in[9],  *wo3 = (const float*)d_in[12];
    const float* wd0 = (const float*)d_in[4],  *wd1 = (const float*)d_in[7],
               *wd2 = (const float*)d_in[10], *wd3 = (const float*)d_in[13];
    const float* bd0 = (const float*)d_in[5],  *bd1 = (const float*)d_in[8],
               *bd2 = (const float*)d_in[11], *bd3 = (const float*)d_in[14];
    unsigned short* ws = (unsigned short*)d_ws;
    float* dout = (float*)d_out;

    void* args[] = { (void*)&X1, (void*)&X2, (void*)&w_bot,
                     (void*)&wo0, (void*)&wo1, (void*)&wo2, (void*)&wo3,
                     (void*)&wd0, (void*)&wd1, (void*)&wd2, (void*)&wd3,
                     (void*)&bd0, (void*)&bd1, (void*)&bd2, (void*)&bd3,
                     (void*)&dout, (void*)&ws };
    hipError_t err = hipLaunchCooperativeKernel((const void*)mega, dim3(256), dim3(512),
                                                args, 0, stream);
    if (err != hipSuccess) {
        (void)hipGetLastError();   // clear error, fall back to plain launches
        k_prep<<<256, 512, 0, stream>>>(X1, X2, w_bot, wo0, wo1, wo2, wo3,
                                        wd0, wd1, wd2, wd3, ws);
        k_bot<<<256, 512, 0, stream>>>(ws + O_IN, ws + O_WBB, ws + O_FA);
        unsigned short* cur = ws + O_FA;
        unsigned short* nxt = ws + O_FB;
        for (int it = 0; it < 4; ++it) {
            const float* bdL = it == 0 ? bd0 : it == 1 ? bd1 : it == 2 ? bd2 : bd3;
            void* outp = (it == 3) ? d_out : (void*)nxt;
            k_layer<<<256, 512, 0, stream>>>(cur, ws + O_WBO + it * 82944,
                                             ws + O_WDB + it * 27648, bdL,
                                             outp, it == 3 ? 1 : 0);
            unsigned short* t = cur; cur = nxt; nxt = t;
        }
    }
}

// Round 12
// 118.964 us; speedup vs baseline: 4.7175x; 4.7175x over previous
//
#include <hip/hip_runtime.h>

#define HW 16384   // 128*128
#define RSB 130    // padded row stride (pixels)

typedef short short8 __attribute__((ext_vector_type(8)));
typedef float f32x4 __attribute__((ext_vector_type(4)));
typedef unsigned short ushort8v __attribute__((ext_vector_type(8)));

__device__ __forceinline__ float b2f(unsigned short u) {
    return __uint_as_float(((unsigned)u) << 16);
}
__device__ __forceinline__ unsigned short f2b(float f) {
    unsigned u = __float_as_uint(f);
    return (unsigned short)((u + 0x7fffu + ((u >> 16) & 1u)) >> 16);
}

// ---------------------------------------------------------------------------
// One-shot prep: weight B-fragments + NHWC pack + border zeroing.
// Grid-stride over 1,026,240 items (512 blocks x 256 thr).
// Fragment orders verified by r8-r10 passing runs.
// ---------------------------------------------------------------------------
__global__ __launch_bounds__(256) void prep_all(
    const float* __restrict__ X1, const float* __restrict__ X2,
    const float* __restrict__ w_bot,
    const float* __restrict__ wo0, const float* __restrict__ wo1,
    const float* __restrict__ wo2, const float* __restrict__ wo3,
    const float* __restrict__ wd0, const float* __restrict__ wd1,
    const float* __restrict__ wd2, const float* __restrict__ wd3,
    unsigned short* __restrict__ wBbot, unsigned short* __restrict__ wBoff,
    unsigned short* __restrict__ wdB,  unsigned short* __restrict__ in_nhwc,
    unsigned short* __restrict__ featA, unsigned short* __restrict__ featB) {
    const int N0 = 165888, N1 = N0 + 331776, N2 = N1 + 110592,
              N3 = N2 + 393216, N4 = N3 + 24768;
    for (int idx = blockIdx.x * 256 + threadIdx.x; idx < N4; idx += 131072) {
        if (idx < N0) {                           // bot conv B-frags (KC=6)
            int i = idx;
            int v = i & 7, lane = (i >> 3) & 63, t = i >> 9;
            int kc = t % 6; t /= 6;
            int tap = t % 9, nt = t / 9;
            int oc = nt * 16 + (lane & 15), cin = kc * 32 + (lane >> 4) * 8 + v;
            wBbot[i] = f2b(oc < 96 ? w_bot[(oc * 192 + cin) * 9 + tap] : 0.f);
        } else if (idx < N1) {                    // offset conv B-frags (KC=3)
            int j = idx - N0;
            int l = j / 82944, i = j - l * 82944;
            const float* w = l == 0 ? wo0 : l == 1 ? wo1 : l == 2 ? wo2 : wo3;
            int v = i & 7, lane = (i >> 3) & 63, t = i >> 9;
            int kc = t % 3; t /= 3;
            int tap = t % 9, nt = t / 9;
            int oc = nt * 16 + (lane & 15), cin = kc * 32 + (lane >> 4) * 8 + v;
            wBoff[j] = f2b(oc < 81 ? w[(oc * 96 + cin) * 9 + tap] : 0.f);
        } else if (idx < N2) {                    // dcn grouped B-frags
            int j = idx - N1;
            int l = j / 27648, i = j - l * 27648;
            const float* w = l == 0 ? wd0 : l == 1 ? wd1 : l == 2 ? wd2 : wd3;
            int v = i & 7, lane = (i >> 3) & 63, t = i >> 9;
            int nt = t & 1; t >>= 1;
            int tap = t % 9, g = t / 9;
            int oc = nt * 16 + (lane & 15), c = (lane >> 4) * 8 + v;
            wdB[j] = f2b(w[((g * 32 + oc) * 32 + c) * 9 + tap]);
        } else if (idx < N3) {                    // pack cat(X1,X2) -> NHWC bf16
            int j = idx - N2;
            int cb = j >> 14, p = j & (HW - 1);
            int ch = cb * 8;
            int y = p >> 7, x = p & 127;
            ushort8v o;
#pragma unroll
            for (int q = 0; q < 8; ++q) {
                int c = ch + q;
                float v = (c < 96) ? X1[c * HW + p] : X2[(c - 96) * HW + p];
                o[q] = f2b(v);
            }
            *(ushort8v*)(in_nhwc + (size_t)((y + 1) * RSB + (x + 1)) * 192 + ch) = o;
        } else {                                  // border zeroing
            int j = idx - N3;
            int bp = j / 48, c8 = j - bp * 48;
            int y, x;
            if (bp < 130)      { y = 0;   x = bp; }
            else if (bp < 260) { y = 129; x = bp - 130; }
            else { int t2 = bp - 260; y = 1 + (t2 >> 1); x = (t2 & 1) ? 129 : 0; }
            size_t pix = (size_t)y * RSB + x;
            ushort8v z = {0, 0, 0, 0, 0, 0, 0, 0};
            if (c8 < 24)      *(ushort8v*)(in_nhwc + pix * 192 + c8 * 8) = z;
            else if (c8 < 36) *(ushort8v*)(featA + pix * 96 + (c8 - 24) * 8) = z;
            else              *(ushort8v*)(featB + pix * 96 + (c8 - 36) * 8) = z;
        }
    }
}

// ---------------------------------------------------------------------------
// Bottom conv (192 -> 96) as 9-tap implicit MFMA GEMM.  (r8-proven)
// Grid 512 x 256 thr; block = 32 px, 4 waves = 2 msub x 2 nh.
// ---------------------------------------------------------------------------
__global__ __launch_bounds__(256) void conv_bot(const unsigned short* __restrict__ in,
                                                const unsigned short* __restrict__ wB,
                                                unsigned short* __restrict__ outb) {
    const int tid = threadIdx.x;
    const int lane = tid & 63;
    const int wid = tid >> 6;
    const int msub = wid & 1, nh = wid >> 1;
    const int pbase = blockIdx.x * 32 + msub * 16;
    const int p = pbase + (lane & 15);
    const int y = p >> 7, x = p & 127;
    const int klane = lane >> 4;
    const unsigned short* arow = in + (size_t)((y + 1) * RSB + (x + 1)) * 192 + klane * 8;
    const unsigned short* wb = wB + (size_t)(nh * 3) * 9 * 6 * 512 + lane * 8;

    f32x4 a0 = {0.f, 0.f, 0.f, 0.f};
    f32x4 a1 = {0.f, 0.f, 0.f, 0.f};
    f32x4 a2 = {0.f, 0.f, 0.f, 0.f};
#pragma unroll
    for (int tap = 0; tap < 9; ++tap) {
        const unsigned short* at = arow + ((tap / 3 - 1) * RSB + (tap % 3 - 1)) * 192;
#pragma unroll
        for (int kc = 0; kc < 6; ++kc) {
            short8 a  = *(const short8*)(at + kc * 32);
            short8 b0 = *(const short8*)(wb + ((0 * 9 + tap) * 6 + kc) * 512);
            short8 b1 = *(const short8*)(wb + ((1 * 9 + tap) * 6 + kc) * 512);
            short8 b2 = *(const short8*)(wb + ((2 * 9 + tap) * 6 + kc) * 512);
            a0 = __builtin_amdgcn_mfma_f32_16x16x32_bf16(a, b0, a0, 0, 0, 0);
            a1 = __builtin_amdgcn_mfma_f32_16x16x32_bf16(a, b1, a1, 0, 0, 0);
            a2 = __builtin_amdgcn_mfma_f32_16x16x32_bf16(a, b2, a2, 0, 0, 0);
        }
    }
    const int col = lane & 15;
#pragma unroll
    for (int r = 0; r < 4; ++r) {
        int pr = pbase + klane * 4 + r;
        int yy = pr >> 7, xx = pr & 127;
        size_t base = (size_t)((yy + 1) * RSB + (xx + 1)) * 96;
        outb[base + (nh * 3 + 0) * 16 + col] = f2b(a0[r]);
        outb[base + (nh * 3 + 1) * 16 + col] = f2b(a1[r]);
        outb[base + (nh * 3 + 2) * 16 + col] = f2b(a2[r]);
    }
}

// ---------------------------------------------------------------------------
// FUSED offset-conv + DCN layer.  Block = 512 thr (8 waves) = 64 pixels.
// Phase A: offset conv -> raw f32 offsets in LDS s_off[64][97].
// Phase B: DCN with precomputed gather addresses + 3-deep pipelined gathers.
// Grid 256, XCD-swizzled to contiguous 16-row bands.
// ---------------------------------------------------------------------------
__global__ __launch_bounds__(512) void offdcn_kernel(
    const unsigned short* __restrict__ feat,
    const unsigned short* __restrict__ wBoff,
    const unsigned short* __restrict__ wdB,
    const float* __restrict__ b_d,
    void* __restrict__ outp, int last) {
    __shared__ float s_off[64][97];

    const int tid = threadIdx.x;
    const int lane = tid & 63;
    const int w = tid >> 6;
    const int col = lane & 15, klane = lane >> 4;
    const int pb = ((blockIdx.x & 7) << 5) + (blockIdx.x >> 3);
    const int P0 = pb * 64;

    // ---------------- phase A: offset conv ----------------
    {
        const int pf = w >> 1, nh = w & 1;
        const int p = P0 + pf * 16 + col;
        const int y = p >> 7, x = p & 127;
        const unsigned short* arow = feat + (size_t)((y + 1) * RSB + (x + 1)) * 96 + klane * 8;
        const unsigned short* wb = wBoff + (size_t)(nh * 3) * 9 * 3 * 512 + lane * 8;

        f32x4 a0 = {0.f, 0.f, 0.f, 0.f};
        f32x4 a1 = {0.f, 0.f, 0.f, 0.f};
        f32x4 a2 = {0.f, 0.f, 0.f, 0.f};
#pragma unroll
        for (int tap = 0; tap < 9; ++tap) {
            const unsigned short* at = arow + ((tap / 3 - 1) * RSB + (tap % 3 - 1)) * 96;
#pragma unroll
            for (int kc = 0; kc < 3; ++kc) {
                short8 a  = *(const short8*)(at + kc * 32);
                short8 b0 = *(const short8*)(wb + ((0 * 9 + tap) * 3 + kc) * 512);
                short8 b1 = *(const short8*)(wb + ((1 * 9 + tap) * 3 + kc) * 512);
                short8 b2 = *(const short8*)(wb + ((2 * 9 + tap) * 3 + kc) * 512);
                a0 = __builtin_amdgcn_mfma_f32_16x16x32_bf16(a, b0, a0, 0, 0, 0);
                a1 = __builtin_amdgcn_mfma_f32_16x16x32_bf16(a, b1, a1, 0, 0, 0);
                a2 = __builtin_amdgcn_mfma_f32_16x16x32_bf16(a, b2, a2, 0, 0, 0);
            }
        }
#pragma unroll
        for (int r = 0; r < 4; ++r) {
            int pl = pf * 16 + klane * 4 + r;
            s_off[pl][nh * 48 + 0 * 16 + col] = a0[r];
            s_off[pl][nh * 48 + 1 * 16 + col] = a1[r];
            s_off[pl][nh * 48 + 2 * 16 + col] = a2[r];
        }
    }
    __syncthreads();

    // ---------------- phase B: DCN, pipelined gathers ----------------
    for (int sidx = w; sidx < 12; sidx += 8) {
        const int pf = sidx & 3, g = sidx >> 2;
        const int p = P0 + pf * 16 + col;
        const int y = p >> 7, x = p & 127;
        const int pl = pf * 16 + col;
        const int coct = klane * 8;

        const unsigned short* fgc = feat + g * 32 + coct;
        const unsigned short* wb = wdB + (size_t)g * 9 * 2 * 512 + lane * 8;

        // precompute ALL gather addresses + bilinear weights (m folded in)
        int adr[9][4];
        float wgt[9][4];
#pragma unroll
        for (int k = 0; k < 9; ++k) {
            float dy = s_off[pl][g * 9 + k];
            float dx = s_off[pl][27 + g * 9 + k];
            float mr = s_off[pl][54 + g * 9 + k];
            float m = 1.f / (1.f + __expf(-mr));

            float py = dy + (float)y + (float)(k / 3 - 1);
            float px = dx + (float)x + (float)(k % 3 - 1);
            float y0f = floorf(py), x0f = floorf(px);
            float fy = py - y0f, fx = px - x0f;

            float vy0 = (y0f >= 0.f   && y0f <= 127.f) ? 1.f : 0.f;
            float vy1 = (y0f >= -1.f  && y0f <= 126.f) ? 1.f : 0.f;
            float vx0 = (x0f >= 0.f   && x0f <= 127.f) ? 1.f : 0.f;
            float vx1 = (x0f >= -1.f  && x0f <= 126.f) ? 1.f : 0.f;

            int iy0r = (int)y0f, ix0r = (int)x0f;
            int iy0 = min(max(iy0r, 0), 127);
            int iy1 = min(max(iy0r + 1, 0), 127);
            int ix0 = min(max(ix0r, 0), 127);
            int ix1 = min(max(ix0r + 1, 0), 127);

            wgt[k][0] = (1.f - fy) * (1.f - fx) * vy0 * vx0 * m;
            wgt[k][1] = (1.f - fy) * fx        * vy0 * vx1 * m;
            wgt[k][2] = fy        * (1.f - fx) * vy1 * vx0 * m;
            wgt[k][3] = fy        * fx         * vy1 * vx1 * m;

            adr[k][0] = (iy0 + 1) * RSB + ix0 + 1;
            adr[k][1] = (iy0 + 1) * RSB + ix1 + 1;
            adr[k][2] = (iy1 + 1) * RSB + ix0 + 1;
            adr[k][3] = (iy1 + 1) * RSB + ix1 + 1;
        }

        f32x4 acc0 = {0.f, 0.f, 0.f, 0.f};
        f32x4 acc1 = {0.f, 0.f, 0.f, 0.f};

        ushort8v ga[4], gb[4], gc[4];
#define LDG(buf, kk) { \
        buf[0] = *(const ushort8v*)(fgc + (size_t)adr[kk][0] * 96); \
        buf[1] = *(const ushort8v*)(fgc + (size_t)adr[kk][1] * 96); \
        buf[2] = *(const ushort8v*)(fgc + (size_t)adr[kk][2] * 96); \
        buf[3] = *(const ushort8v*)(fgc + (size_t)adr[kk][3] * 96); }
#define CMP(buf, kk) { \
        short8 a; \
        _Pragma("unroll") for (int j = 0; j < 8; ++j) { \
            float val = wgt[kk][0] * b2f(buf[0][j]) + wgt[kk][1] * b2f(buf[1][j]) \
                      + wgt[kk][2] * b2f(buf[2][j]) + wgt[kk][3] * b2f(buf[3][j]); \
            a[j] = (short)f2b(val); } \
        short8 b0 = *(const short8*)(wb + ((kk) * 2 + 0) * 512); \
        short8 b1 = *(const short8*)(wb + ((kk) * 2 + 1) * 512); \
        acc0 = __builtin_amdgcn_mfma_f32_16x16x32_bf16(a, b0, acc0, 0, 0, 0); \
        acc1 = __builtin_amdgcn_mfma_f32_16x16x32_bf16(a, b1, acc1, 0, 0, 0); }

        LDG(ga, 0); LDG(gb, 1); LDG(gc, 2);
        CMP(ga, 0); LDG(ga, 3);
        CMP(gb, 1); LDG(gb, 4);
        CMP(gc, 2); LDG(gc, 5);
        CMP(ga, 3); LDG(ga, 6);
        CMP(gb, 4); LDG(gb, 7);
        CMP(gc, 5); LDG(gc, 8);
        CMP(ga, 6); CMP(gb, 7); CMP(gc, 8);
#undef LDG
#undef CMP

#pragma unroll
        for (int r = 0; r < 4; ++r) {
            int pr = P0 + pf * 16 + klane * 4 + r;
            int ch0 = g * 32 + col, ch1 = g * 32 + 16 + col;
            float o0 = acc0[r] + b_d[ch0];
            float o1 = acc1[r] + b_d[ch1];
            if (!last) {
                int yy = pr >> 7, xx = pr & 127;
                unsigned short* fo = (unsigned short*)outp;
                size_t base = (size_t)((yy + 1) * RSB + (xx + 1)) * 96;
                fo[base + ch0] = f2b(o0);
                fo[base + ch1] = f2b(o1);
            } else {
                float* fo = (float*)outp;
                fo[(size_t)ch0 * HW + pr] = o0;
                fo[(size_t)ch1 * HW + pr] = o1;
            }
        }
    }
}

// ---------------------------------------------------------------------------
extern "C" void kernel_launch(void* const* d_in, const int* in_sizes, int n_in,
                              void* d_out, int out_size, void* d_ws, size_t ws_size,
                              hipStream_t stream) {
    const float* X1    = (const float*)d_in[0];
    const float* X2    = (const float*)d_in[1];
    const float* w_bot = (const float*)d_in[2];
    const float* wo0 = (const float*)d_in[3],  *wo1 = (const float*)d_in[6],
               *wo2 = (const float*)d_in[9],  *wo3 = (const float*)d_in[12];
    const float* wd0 = (const float*)d_in[4],  *wd1 = (const float*)d_in[7],
               *wd2 = (const float*)d_in[10], *wd3 = (const float*)d_in[13];
    const float* bd[4] = {(const float*)d_in[5], (const float*)d_in[8],
                          (const float*)d_in[11], (const float*)d_in[14]};

    // workspace layout (ushort units):
    unsigned short* in_nhwc = (unsigned short*)d_ws;          // 3,244,800
    unsigned short* featA   = in_nhwc + 3244800;              // 1,622,400
    unsigned short* featB   = featA + 1622400;                // 1,622,400
    unsigned short* wBbot   = featB + 1622400;                // 165,888
    unsigned short* wBoff   = wBbot + 165888;                 // 4 x 82,944
    unsigned short* wdB     = wBoff + 4 * 82944;              // 4 x 27,648
    // total 7,097,856 ushorts = 14.2 MB

    prep_all<<<512, 256, 0, stream>>>(X1, X2, w_bot, wo0, wo1, wo2, wo3,
                                      wd0, wd1, wd2, wd3,
                                      wBbot, wBoff, wdB, in_nhwc, featA, featB);
    conv_bot<<<512, 256, 0, stream>>>(in_nhwc, wBbot, featA);

    unsigned short* cur = featA;
    unsigned short* nxt = featB;
    for (int it = 0; it < 4; ++it) {
        void* outp = (it == 3) ? d_out : (void*)nxt;
        offdcn_kernel<<<256, 512, 0, stream>>>(cur, wBoff + it * 82944,
                                               wdB + it * 27648, bd[it],
                                               outp, it == 3 ? 1 : 0);
        unsigned short* t = cur; cur = nxt; nxt = t;
    }
}